// Round 13
// baseline (231.855 us; speedup 1.0000x reference)
//
#include <hip/hip_runtime.h>
#include <cstdint>

#define NN   100000
#define NE   1600000
#define FIN  128
#define HH1  128
#define HH2  64
#define NC   10
#define NG   64

#define NB   1024          // fine buckets (= NCB*NCB)
#define NPB  98            // nodes per fine bucket
#define BCAP 2048          // per-fine-bucket capacity (max padded bucket < 2048, verified)
#define NCB  32            // coarse buckets
#define NPCB 3136          // nodes per coarse bucket (32*98)
#define CCAP 53248         // per-coarse capacity (26*2048; expected 50k, 13-sigma margin)
#define EPS  2048          // edges per split block
#define NBLK1 ((NE + EPS - 1) / EPS)   // 782
#define SLICES (CCAP / EPS)            // 26

typedef __attribute__((ext_vector_type(8))) short bf16x8;
typedef __attribute__((ext_vector_type(4))) float f32x4;
typedef __attribute__((ext_vector_type(2))) float f32x2;

#if defined(__has_builtin)
#  if __has_builtin(__builtin_amdgcn_cvt_pk_f32_fp8) && \
      __has_builtin(__builtin_amdgcn_cvt_f32_fp8) && \
      __has_builtin(__builtin_amdgcn_cvt_pk_fp8_f32)
#    define HW_FP8 1
#  endif
#endif
#ifndef HW_FP8
#  define HW_FP8 0
#endif

__device__ __forceinline__ unsigned pack2(float a, float b) {
    union { float f; unsigned u; } x, y; x.f = a; y.f = b;
    const unsigned lo = x.u + 0x7fffu + ((x.u >> 16) & 1u);
    const unsigned hi = y.u + 0x7fffu + ((y.u >> 16) & 1u);
    return (lo >> 16) | (hi & 0xffff0000u);
}

// ---- fp8 e4m3 encode/decode (HW converts when available; SW fallback is
// self-consistent, so correctness never depends on the HW format) ----
__device__ __forceinline__ float sw_dec8(unsigned b) {
    const unsigned s = b >> 7, e = (b >> 3) & 15u, m = b & 7u;
    float v;
    if (e == 0) v = (float)m * 0.001953125f;               // m * 2^-9
    else { union { unsigned u; float f; } y; y.u = ((e + 120u) << 23) | (m << 20); v = y.f; }
    return s ? -v : v;
}
__device__ __forceinline__ unsigned sw_enc8(float f) {
    union { float f; unsigned u; } x; x.f = f;
    const unsigned s = (x.u >> 31) << 7;
    float a = fabsf(f);
    a = fminf(a, 448.0f);
    unsigned ia;
    if (a < 0.015625f) {
        ia = (unsigned)(int)rintf(a * 512.0f);
    } else {
        union { float f; unsigned u; } y; y.f = a;
        int e = (int)((y.u >> 23) & 255u) - 127;
        unsigned keep = (y.u >> 20) & 7u;
        const unsigned rest = y.u & 0xfffffu;
        keep += (rest > 0x80000u) || (rest == 0x80000u && (keep & 1u));
        if (keep == 8u) { keep = 0u; e += 1; }
        if (e >= 8) { e = 8; if (keep > 6u) keep = 6u; }
        ia = ((unsigned)(e + 7) << 3) | keep;
    }
    return s | ia;
}
// decode 4 fp8 bytes of a uint -> 4 floats
__device__ __forceinline__ f32x4 fp8x4_f32(unsigned u) {
#if HW_FP8
    f32x2 lo = __builtin_amdgcn_cvt_pk_f32_fp8(u, false);
    f32x2 hi = __builtin_amdgcn_cvt_pk_f32_fp8(u, true);
    return (f32x4){lo[0], lo[1], hi[0], hi[1]};
#else
    return (f32x4){sw_dec8(u & 0xffu), sw_dec8((u >> 8) & 0xffu),
                   sw_dec8((u >> 16) & 0xffu), sw_dec8(u >> 24)};
#endif
}
__device__ __forceinline__ float fp8_f32(unsigned b) {       // decode byte 0
#if HW_FP8
    return __builtin_amdgcn_cvt_f32_fp8(b, 0);
#else
    return sw_dec8(b & 0xffu);
#endif
}
__device__ __forceinline__ unsigned f32_fp8(float a) {       // encode -> byte
#if HW_FP8
    return __builtin_amdgcn_cvt_pk_fp8_f32(a, a, 0u, false) & 0xffu;
#else
    return sw_enc8(a);
#endif
}
// pack 4 floats -> 4 fp8 bytes in a uint
__device__ __forceinline__ unsigned pack4_fp8(float a, float b, float c, float d) {
#if HW_FP8
    unsigned u = __builtin_amdgcn_cvt_pk_fp8_f32(a, b, 0u, false);
    u = __builtin_amdgcn_cvt_pk_fp8_f32(c, d, u, true);
    return u;
#else
    return sw_enc8(a) | (sw_enc8(b) << 8) | (sw_enc8(c) << 16) | (sw_enc8(d) << 24);
#endif
}

// init: coarse/fine cursors to fixed-capacity bases; zero sums/cnt
__global__ __launch_bounds__(256) void k_init(int* __restrict__ gcur1,
                                              int* __restrict__ gcur2,
                                              float* __restrict__ sums) {
    const int i = blockIdx.x * blockDim.x + threadIdx.x;
    if (i < NCB) gcur1[i] = i * CCAP;
    if (i < NB)  gcur2[i] = i * BCAP;
    if (i < NG * HH2 + NG) sums[i] = 0.f;
}

// pass 1: split edges into 32 coarse buckets by dst/3136; pack (src<<12 | dst%3136).
// 2048 edges/block, 32-entry LDS histogram -> ~64-entry (256 B) contiguous runs per bucket.
__global__ __launch_bounds__(256) void k_split1(const int* __restrict__ src,
                                                const int* __restrict__ dst,
                                                int* __restrict__ gcur1,
                                                unsigned* __restrict__ pairs1, int E) {
    __shared__ int bcnt[NCB];
    __shared__ int bglob[NCB];
    const int t = threadIdx.x;
    if (t < NCB) bcnt[t] = 0;
    __syncthreads();
    const int base = blockIdx.x * EPS;
    unsigned val[8]; int bo[8];
#pragma unroll
    for (int i = 0; i < 8; ++i) {
        const int e = base + i * 256 + t;
        if (e < E) {
            const int d = dst[e], s = src[e];
            const int c = d / NPCB;
            val[i] = ((unsigned)s << 12) | (unsigned)(d - c * NPCB);
            const int l = atomicAdd(&bcnt[c], 1);
            bo[i] = (c << 16) | l;
        } else bo[i] = -1;
    }
    __syncthreads();
    if (t < NCB && bcnt[t] > 0) bglob[t] = atomicAdd(&gcur1[t], bcnt[t]);
    __syncthreads();
#pragma unroll
    for (int i = 0; i < 8; ++i) {
        if (bo[i] >= 0) {
            const int c = bo[i] >> 16, l = bo[i] & 0xffff;
            pairs1[bglob[c] + l] = val[i];
        }
    }
}

// pass 2: split each coarse stream into 32 fine buckets; repack (src<<7 | dst%98).
// 26 slice-blocks per coarse bucket.
__global__ __launch_bounds__(256) void k_split2(const unsigned* __restrict__ pairs1,
                                                const int* __restrict__ gcur1,
                                                int* __restrict__ gcur2,
                                                unsigned* __restrict__ pairs2) {
    __shared__ int bcnt[NCB];
    __shared__ int bglob[NCB];
    const int t = threadIdx.x;
    const int c = blockIdx.x / SLICES;
    const int sidx = blockIdx.x % SLICES;
    const int start = c * CCAP + sidx * EPS;
    const int cend = gcur1[c];
    if (t < NCB) bcnt[t] = 0;
    __syncthreads();
    unsigned val[8]; int bo[8];
#pragma unroll
    for (int i = 0; i < 8; ++i) {
        const int e = start + i * 256 + t;
        if (e < cend) {
            const unsigned p = pairs1[e];
            const unsigned r = p & 4095u;
            const int f = (int)r / NPB;
            val[i] = ((p >> 12) << 7) | (r - (unsigned)(f * NPB));
            const int l = atomicAdd(&bcnt[f], 1);
            bo[i] = (f << 16) | l;
        } else bo[i] = -1;
    }
    __syncthreads();
    if (t < NCB && bcnt[t] > 0) bglob[t] = atomicAdd(&gcur2[c * NCB + t], bcnt[t]);
    __syncthreads();
#pragma unroll
    for (int i = 0; i < 8; ++i) {
        if (bo[i] >= 0) {
            const int f = bo[i] >> 16, l = bo[i] & 0xffff;
            pairs2[bglob[f] + l] = val[i];
        }
    }
}

// per-bucket CSR finalize. One block per fine bucket; ebeg = b*BCAP, eend = gcur2[b].
// Row starts 4-ALIGNED (degrees padded to mult-of-4; gaps unread).
__global__ __launch_bounds__(256) void k_csr(const unsigned* __restrict__ pairs,
                                             const int* __restrict__ gcur2,
                                             int* __restrict__ row_start,
                                             int* __restrict__ rend,
                                             float* __restrict__ dinv,
                                             int* __restrict__ esrc) {
    const int b = blockIdx.x;
    const int node0 = b * NPB;
    if (node0 >= NN) return;
    const int nn = min(NPB, NN - node0);
    __shared__ int cnt[NPB];
    __shared__ int scn[128];
    __shared__ int cur[NPB];
    const int t = threadIdx.x;
    if (t < NPB) cnt[t] = 0;
    __syncthreads();
    const int ebeg = b * BCAP, eend = gcur2[b];
    for (int j = ebeg + t; j < eend; j += 256)
        atomicAdd(&cnt[pairs[j] & 127u], 1);
    __syncthreads();
    int v = 0, pv = 0;
    if (t < 128) { v = (t < nn) ? cnt[t] : 0; pv = (v + 3) & ~3; scn[t] = pv; }
    __syncthreads();
    for (int off = 1; off < 128; off <<= 1) {
        int x = 0;
        if (t < 128 && t >= off) x = scn[t - off];
        __syncthreads();
        if (t < 128) scn[t] += x;
        __syncthreads();
    }
    if (t < nn) {
        const int rs = ebeg + scn[t] - pv;   // 4-aligned
        row_start[node0 + t] = rs;
        rend[node0 + t]      = rs + v;
        cur[t] = rs;
        dinv[node0 + t] = rsqrtf((float)v + 1.f);
    }
    __syncthreads();
    for (int j = ebeg + t; j < eend; j += 256) {
        const unsigned p = pairs[j];
        const int pos = atomicAdd(&cur[p & 127u], 1);
        esrc[pos] = (int)(p >> 7);
    }
}

// BF16 MFMA GEMM: C[M,BN] = A[M,128] @ B[128,BN]; epilogue scale-by-dinv + fp8 store.
// A fragments loaded DIRECTLY from global (no LDS); B staged in LDS (bf16, swizzled).
template <int BN, bool ABF16>
__global__ __launch_bounds__(256) void k_mfma(const void* __restrict__ Ain,
                                              const float* __restrict__ Bin,
                                              unsigned char* __restrict__ Cout,
                                              const float* __restrict__ rowscale,
                                              int M) {
    __shared__ unsigned short Bs[BN][128];
    const int t = threadIdx.x;
    const int row0 = blockIdx.x * 128;

    // ---- stage B (whole 128-K, transposed, f32 -> bf16, swizzled) ----
    {
        constexpr int KSEG = (BN == 128) ? 64 : 32;
        const int n  = t & (BN - 1);
        const int kb = (t / BN) * KSEG;
#pragma unroll
        for (int i = 0; i < KSEG; i += 2) {
            const int k = kb + i;
            const unsigned u = pack2(Bin[(size_t)k * BN + n], Bin[(size_t)(k + 1) * BN + n]);
            *(unsigned*)&Bs[n][(((k >> 3) ^ (n & 7)) << 3) + (k & 7)] = u;
        }
    }

    const int lane = t & 63, wave = t >> 6;
    const int lr = lane & 15, lg = lane >> 4;
    constexpr int MR = 2;
    constexpr int NR = BN / 16;          // 8 (BN=128) or 4 (BN=64)
    const int wrow = wave * 32;

    // ---- A fragments direct from global (rows >= M clamped; outputs masked) ----
    bf16x8 afrag[4][MR];
#pragma unroll
    for (int m = 0; m < MR; ++m) {
        int row = row0 + wrow + m * 16 + lr;
        row = (row < M) ? row : (M - 1);
        if (ABF16) {
            const uint4* ap = (const uint4*)((const unsigned short*)Ain + (size_t)row * 128);
#pragma unroll
            for (int ks = 0; ks < 4; ++ks) {
                const uint4 v = ap[ks * 4 + lg];
                afrag[ks][m] = *(const bf16x8*)&v;
            }
        } else {
            const float* ap = (const float*)Ain + (size_t)row * 128;
#pragma unroll
            for (int ks = 0; ks < 4; ++ks) {
                const float4 f0 = *(const float4*)(ap + ks * 32 + lg * 8);
                const float4 f1 = *(const float4*)(ap + ks * 32 + lg * 8 + 4);
                const uint4 v = make_uint4(pack2(f0.x, f0.y), pack2(f0.z, f0.w),
                                           pack2(f1.x, f1.y), pack2(f1.z, f1.w));
                afrag[ks][m] = *(const bf16x8*)&v;
            }
        }
    }
    __syncthreads();

    // ---- MFMA ----
    f32x4 acc[MR][NR];
#pragma unroll
    for (int m = 0; m < MR; ++m)
#pragma unroll
        for (int n = 0; n < NR; ++n) acc[m][n] = (f32x4){0.f, 0.f, 0.f, 0.f};

#pragma unroll
    for (int ks = 0; ks < 4; ++ks) {
        const int cc = ((ks * 4 + lg) ^ (lr & 7)) * 8;
        bf16x8 b[NR];
#pragma unroll
        for (int n = 0; n < NR; ++n) b[n] = *(const bf16x8*)&Bs[n * 16 + lr][cc];
#pragma unroll
        for (int m = 0; m < MR; ++m)
#pragma unroll
            for (int n = 0; n < NR; ++n)
                acc[m][n] = __builtin_amdgcn_mfma_f32_16x16x32_bf16(afrag[ks][m], b[n], acc[m][n], 0, 0, 0);
    }

    // ---- epilogue: scale by dinv[row], fp8 store ----
#pragma unroll
    for (int m = 0; m < MR; ++m) {
        const int rb = wrow + m * 16 + lg * 4;
        float s[4]; int gr[4];
#pragma unroll
        for (int j = 0; j < 4; ++j) {
            gr[j] = row0 + rb + j;
            s[j] = (gr[j] < M) ? rowscale[gr[j]] : 0.f;
        }
#pragma unroll
        for (int n = 0; n < NR; ++n) {
            const int col = n * 16 + lr;
#pragma unroll
            for (int j = 0; j < 4; ++j)
                if (gr[j] < M)
                    Cout[(size_t)gr[j] * BN + col] = (unsigned char)f32_fp8(acc[m][n][j] * s[j]);
        }
    }
}

// layer-1 aggregation: one wave/node. Row = 16 uint2 (128 fp8). Quarter-wave per edge;
// main loop loads 16 indices as ONE int4 per lane (row starts 4-aligned).
__global__ __launch_bounds__(256) void k_agg1(const int* __restrict__ row_start,
                                              const int* __restrict__ row_end,
                                              const int* __restrict__ esrc,
                                              const float* __restrict__ dinv,
                                              const uint2* __restrict__ hb,
                                              const float* __restrict__ b,
                                              uint4* __restrict__ outp, int n) {
    const int wid  = (blockIdx.x * blockDim.x + threadIdx.x) >> 6;
    const int lane = threadIdx.x & 63;
    if (wid >= n) return;
    const int q  = lane >> 4;             // 0..3 edge slot
    const int ql = lane & 15;             // uint2 index within row
    const int beg = row_start[wid], end = row_end[wid];

    f32x4 accA = (f32x4){0.f, 0.f, 0.f, 0.f};
    f32x4 accB = accA;
    if (q == 0) {                         // self row once
        const uint2 u = hb[(size_t)wid * 16 + ql];
        accA = fp8x4_f32(u.x);
        accB = fp8x4_f32(u.y);
    }

    int j = beg;
    for (; j + 16 <= end; j += 16) {
        const int4 ix = *(const int4*)&esrc[j + q * 4];   // 16B-aligned (beg mult of 4)
        const uint2 u0 = hb[(size_t)ix.x * 16 + ql];
        const uint2 u1 = hb[(size_t)ix.y * 16 + ql];
        const uint2 u2 = hb[(size_t)ix.z * 16 + ql];
        const uint2 u3 = hb[(size_t)ix.w * 16 + ql];
        accA += (fp8x4_f32(u0.x) + fp8x4_f32(u1.x)) + (fp8x4_f32(u2.x) + fp8x4_f32(u3.x));
        accB += (fp8x4_f32(u0.y) + fp8x4_f32(u1.y)) + (fp8x4_f32(u2.y) + fp8x4_f32(u3.y));
    }
    for (; j + 4 <= end; j += 4) {
        const uint2 u = hb[(size_t)esrc[j + q] * 16 + ql];
        accA += fp8x4_f32(u.x);
        accB += fp8x4_f32(u.y);
    }
    if (j + q < end) {
        const uint2 u = hb[(size_t)esrc[j + q] * 16 + ql];
        accA += fp8x4_f32(u.x);
        accB += fp8x4_f32(u.y);
    }

    // combine quarter-wave partials
#pragma unroll
    for (int k = 0; k < 4; ++k) {
        accA[k] += __shfl_xor(accA[k], 16); accA[k] += __shfl_xor(accA[k], 32);
        accB[k] += __shfl_xor(accB[k], 16); accB[k] += __shfl_xor(accB[k], 32);
    }

    if (q == 0) {
        const float dd = dinv[wid];
        const float4 bv0 = *(const float4*)&b[ql * 8];
        const float4 bv1 = *(const float4*)&b[ql * 8 + 4];
        float r[8];
        r[0] = fmaxf(fmaf(dd, accA[0], bv0.x), 0.f);
        r[1] = fmaxf(fmaf(dd, accA[1], bv0.y), 0.f);
        r[2] = fmaxf(fmaf(dd, accA[2], bv0.z), 0.f);
        r[3] = fmaxf(fmaf(dd, accA[3], bv0.w), 0.f);
        r[4] = fmaxf(fmaf(dd, accB[0], bv1.x), 0.f);
        r[5] = fmaxf(fmaf(dd, accB[1], bv1.y), 0.f);
        r[6] = fmaxf(fmaf(dd, accB[2], bv1.z), 0.f);
        r[7] = fmaxf(fmaf(dd, accB[3], bv1.w), 0.f);
        outp[(size_t)wid * 16 + ql] = make_uint4(pack2(r[0], r[1]), pack2(r[2], r[3]),
                                                 pack2(r[4], r[5]), pack2(r[6], r[7]));
    }
}

// layer-2 aggregation: one wave/node. Row = 8 uint2 (64 fp8). Eighth-wave per edge;
// main loop loads 16 indices as ONE int2 per lane. Output fp8.
__global__ __launch_bounds__(256) void k_agg2(const int* __restrict__ row_start,
                                              const int* __restrict__ row_end,
                                              const int* __restrict__ esrc,
                                              const float* __restrict__ dinv,
                                              const uint2* __restrict__ hb,
                                              const float* __restrict__ b,
                                              uint2* __restrict__ outp, int n) {
    const int wid  = (blockIdx.x * blockDim.x + threadIdx.x) >> 6;
    const int lane = threadIdx.x & 63;
    if (wid >= n) return;
    const int o  = lane >> 3;             // 0..7 edge slot
    const int ol = lane & 7;              // uint2 index within row
    const int beg = row_start[wid], end = row_end[wid];

    f32x4 accA = (f32x4){0.f, 0.f, 0.f, 0.f};
    f32x4 accB = accA;
    if (o == 0) {                         // self row once
        const uint2 u = hb[(size_t)wid * 8 + ol];
        accA = fp8x4_f32(u.x);
        accB = fp8x4_f32(u.y);
    }

    int j = beg;
    for (; j + 16 <= end; j += 16) {
        const int2 ix = *(const int2*)&esrc[j + o * 2];   // 8B-aligned
        const uint2 u0 = hb[(size_t)ix.x * 8 + ol];
        const uint2 u1 = hb[(size_t)ix.y * 8 + ol];
        accA += fp8x4_f32(u0.x) + fp8x4_f32(u1.x);
        accB += fp8x4_f32(u0.y) + fp8x4_f32(u1.y);
    }
    for (; j + 8 <= end; j += 8) {
        const uint2 u = hb[(size_t)esrc[j + o] * 8 + ol];
        accA += fp8x4_f32(u.x);
        accB += fp8x4_f32(u.y);
    }
    if (j + o < end) {
        const uint2 u = hb[(size_t)esrc[j + o] * 8 + ol];
        accA += fp8x4_f32(u.x);
        accB += fp8x4_f32(u.y);
    }

    // combine eighth-wave partials
#pragma unroll
    for (int k = 0; k < 4; ++k) {
        accA[k] += __shfl_xor(accA[k], 8);
        accA[k] += __shfl_xor(accA[k], 16);
        accA[k] += __shfl_xor(accA[k], 32);
        accB[k] += __shfl_xor(accB[k], 8);
        accB[k] += __shfl_xor(accB[k], 16);
        accB[k] += __shfl_xor(accB[k], 32);
    }

    if (o == 0) {
        const float dd = dinv[wid];
        const float4 bv0 = *(const float4*)&b[ol * 8];
        const float4 bv1 = *(const float4*)&b[ol * 8 + 4];
        const unsigned w0 = pack4_fp8(fmaf(dd, accA[0], bv0.x), fmaf(dd, accA[1], bv0.y),
                                      fmaf(dd, accA[2], bv0.z), fmaf(dd, accA[3], bv0.w));
        const unsigned w1 = pack4_fp8(fmaf(dd, accB[0], bv1.x), fmaf(dd, accB[1], bv1.y),
                                      fmaf(dd, accB[2], bv1.z), fmaf(dd, accB[3], bv1.w));
        outp[(size_t)wid * 8 + ol] = make_uint2(w0, w1);
    }
}

// mean-pool: one wave per 128 consecutive nodes (batch sorted), lane = feature (fp8 in)
__global__ __launch_bounds__(256) void k_pool(const unsigned char* __restrict__ v2,
                                              const int* __restrict__ batch,
                                              float* __restrict__ sums,
                                              float* __restrict__ cnt, int n) {
    constexpr int NPW = 128;
    const int gt = blockIdx.x * blockDim.x + threadIdx.x;
    const int wave = gt >> 6;
    const int lane = threadIdx.x & 63;
    const int start = wave * NPW;
    if (start >= n) return;
    const int end = min(start + NPW, n);
    float acc = 0.f, cacc = 0.f;
    int cur = batch[start];
    for (int nd = start; nd < end; ++nd) {
        const int gid = batch[nd];
        if (gid != cur) {
            atomicAdd(&sums[cur * HH2 + lane], acc);
            if (lane == 0) atomicAdd(&cnt[cur], cacc);
            acc = 0.f; cacc = 0.f; cur = gid;
        }
        acc += fp8_f32(v2[(size_t)nd * 64 + lane]);
        cacc += 1.f;
    }
    atomicAdd(&sums[cur * HH2 + lane], acc);
    if (lane == 0) atomicAdd(&cnt[cur], cacc);
}

__global__ void k_fc(const float* __restrict__ sums, const float* __restrict__ cnt,
                     const float* __restrict__ Wfc, const float* __restrict__ bfc,
                     float* __restrict__ out) {
    const int tid = threadIdx.x;
    if (tid >= NG * NC) return;
    const int g = tid / NC;
    const int c = tid % NC;
    float a = 0.f;
    for (int k = 0; k < HH2; ++k)
        a = fmaf(sums[g * HH2 + k], Wfc[k * NC + c], a);
    const float cg = fmaxf(cnt[g], 1.0f);
    out[g * NC + c] = a / cg + bfc[c];
}

extern "C" void kernel_launch(void* const* d_in, const int* in_sizes, int n_in,
                              void* d_out, int out_size, void* d_ws, size_t ws_size,
                              hipStream_t stream) {
    const float* x   = (const float*)d_in[0];
    const int*   ei  = (const int*)d_in[1];
    const int*   bat = (const int*)d_in[2];
    const float* W1  = (const float*)d_in[3];
    const float* b1  = (const float*)d_in[4];
    const float* W2  = (const float*)d_in[5];
    const float* b2  = (const float*)d_in[6];
    const float* Wfc = (const float*)d_in[7];
    const float* bfc = (const float*)d_in[8];
    float* out = (float*)d_out;

    const int* src = ei;
    const int* dst = ei + NE;

    // workspace layout (float/u32 slots):
    // [0, N*64)                  relu1 (uint, bf16 pairs) — later v2 (fp8 N*64 B) reuses
    // [N*64, N*96)               h1b fp8 (N*128 B) — later h2b fp8 (N*64 B) reuses
    // [N*96, N*97)               dinv
    // [N*97, N*98)               row_start
    // [N*98, N*99)               rend
    // [N*99, +NB*BCAP)           esrc   (fine-bucketed, 4-aligned rows)
    // [.., +NB*BCAP)             pairs2 (fine-bucketed packed edges)
    // [.., +NCB*CCAP)            pairs1 (coarse-bucketed packed edges)
    // then sums, cnt, gcur1(NCB), gcur2(NB)
    float* ws = (float*)d_ws;
    unsigned* relu1     = (unsigned*)ws;
    unsigned char* v2   = (unsigned char*)ws;
    unsigned char* h1b  = (unsigned char*)(ws + (size_t)NN * 64);
    unsigned char* h2b  = (unsigned char*)(ws + (size_t)NN * 64);
    float*    dinv      = ws + (size_t)NN * 96;
    int*      row_start = (int*)(ws + (size_t)NN * 97);
    int*      rend      = (int*)(ws + (size_t)NN * 98);
    int*      esrc      = (int*)(ws + (size_t)NN * 99);
    unsigned* pairs2    = (unsigned*)(ws + (size_t)NN * 99 + (size_t)NB * BCAP);
    unsigned* pairs1    = (unsigned*)(ws + (size_t)NN * 99 + 2 * (size_t)NB * BCAP);
    float*    sums      = ws + (size_t)NN * 99 + 2 * (size_t)NB * BCAP + (size_t)NCB * CCAP;
    float*    cntf      = sums + NG * HH2;
    int*      gcur1     = (int*)(cntf + NG);          // NCB entries
    int*      gcur2     = gcur1 + NCB;                // NB entries

    // ---- init + two-level radix CSR build ----
    k_init<<<(NG * HH2 + NG + 255) / 256, 256, 0, stream>>>(gcur1, gcur2, sums);
    k_split1<<<NBLK1, 256, 0, stream>>>(src, dst, gcur1, pairs1, NE);
    k_split2<<<NCB * SLICES, 256, 0, stream>>>(pairs1, gcur1, gcur2, pairs2);
    k_csr<<<NB, 256, 0, stream>>>(pairs2, gcur2, row_start, rend, dinv, esrc);

    const int gblk = (NN + 127) / 128;   // 782

    // ---- layer 1: h1b = fp8(dinv[row] * (x @ W1)) via MFMA ----
    k_mfma<128, false><<<gblk, 256, 0, stream>>>(x, W1, h1b, dinv, NN);
    k_agg1<<<(NN * 64 + 255) / 256, 256, 0, stream>>>(row_start, rend, esrc, dinv,
                                                      (const uint2*)h1b, b1,
                                                      (uint4*)relu1, NN);

    // ---- layer 2: h2b = fp8(dinv[row] * (relu1 @ W2)) via MFMA ----
    k_mfma<64, true><<<gblk, 256, 0, stream>>>(relu1, W2, h2b, dinv, NN);
    k_agg2<<<(NN * 64 + 255) / 256, 256, 0, stream>>>(row_start, rend, esrc, dinv,
                                                      (const uint2*)h2b, b2,
                                                      (uint2*)v2, NN);

    // ---- pool ----
    {
        const int waves = (NN + 127) / 128;
        const int blocks = (waves * 64 + 255) / 256;
        k_pool<<<blocks, 256, 0, stream>>>(v2, bat, sums, cntf, NN);
    }

    // ---- final FC ----
    k_fc<<<1, 640, 0, stream>>>(sums, cntf, Wfc, bfc, out);
}

// Round 14
// 223.436 us; speedup vs baseline: 1.0377x; 1.0377x over previous
//
#include <hip/hip_runtime.h>
#include <cstdint>

#define NN   100000
#define NE   1600000
#define FIN  128
#define HH1  128
#define HH2  64
#define NC   10
#define NG   64

#define NB   256           // buckets
#define NPB  392           // nodes per bucket (256*392 >= 100000)
#define BCAP 8192          // fixed per-bucket capacity (max padded bucket ~7750)
#define EPB  8192          // edges per block in bucket passes
#define NBLK_B ((NE + EPB - 1) / EPB)   // 196

typedef __attribute__((ext_vector_type(8))) short bf16x8;
typedef __attribute__((ext_vector_type(4))) float f32x4;
typedef __attribute__((ext_vector_type(2))) float f32x2;

#if defined(__has_builtin)
#  if __has_builtin(__builtin_amdgcn_cvt_pk_f32_fp8) && \
      __has_builtin(__builtin_amdgcn_cvt_f32_fp8) && \
      __has_builtin(__builtin_amdgcn_cvt_pk_fp8_f32)
#    define HW_FP8 1
#  endif
#endif
#ifndef HW_FP8
#  define HW_FP8 0
#endif

__device__ __forceinline__ unsigned pack2(float a, float b) {
    union { float f; unsigned u; } x, y; x.f = a; y.f = b;
    const unsigned lo = x.u + 0x7fffu + ((x.u >> 16) & 1u);
    const unsigned hi = y.u + 0x7fffu + ((y.u >> 16) & 1u);
    return (lo >> 16) | (hi & 0xffff0000u);
}

// ---- fp8 e4m3 encode/decode (HW converts when available; SW fallback is
// self-consistent, so correctness never depends on the HW format) ----
__device__ __forceinline__ float sw_dec8(unsigned b) {
    const unsigned s = b >> 7, e = (b >> 3) & 15u, m = b & 7u;
    float v;
    if (e == 0) v = (float)m * 0.001953125f;               // m * 2^-9
    else { union { unsigned u; float f; } y; y.u = ((e + 120u) << 23) | (m << 20); v = y.f; }
    return s ? -v : v;
}
__device__ __forceinline__ unsigned sw_enc8(float f) {
    union { float f; unsigned u; } x; x.f = f;
    const unsigned s = (x.u >> 31) << 7;
    float a = fabsf(f);
    a = fminf(a, 448.0f);
    unsigned ia;
    if (a < 0.015625f) {
        ia = (unsigned)(int)rintf(a * 512.0f);
    } else {
        union { float f; unsigned u; } y; y.f = a;
        int e = (int)((y.u >> 23) & 255u) - 127;
        unsigned keep = (y.u >> 20) & 7u;
        const unsigned rest = y.u & 0xfffffu;
        keep += (rest > 0x80000u) || (rest == 0x80000u && (keep & 1u));
        if (keep == 8u) { keep = 0u; e += 1; }
        if (e >= 8) { e = 8; if (keep > 6u) keep = 6u; }
        ia = ((unsigned)(e + 7) << 3) | keep;
    }
    return s | ia;
}
// decode 4 fp8 bytes of a uint -> 4 floats
__device__ __forceinline__ f32x4 fp8x4_f32(unsigned u) {
#if HW_FP8
    f32x2 lo = __builtin_amdgcn_cvt_pk_f32_fp8(u, false);
    f32x2 hi = __builtin_amdgcn_cvt_pk_f32_fp8(u, true);
    return (f32x4){lo[0], lo[1], hi[0], hi[1]};
#else
    return (f32x4){sw_dec8(u & 0xffu), sw_dec8((u >> 8) & 0xffu),
                   sw_dec8((u >> 16) & 0xffu), sw_dec8(u >> 24)};
#endif
}
__device__ __forceinline__ float fp8_f32(unsigned b) {       // decode byte 0
#if HW_FP8
    return __builtin_amdgcn_cvt_f32_fp8(b, 0);
#else
    return sw_dec8(b & 0xffu);
#endif
}
__device__ __forceinline__ unsigned f32_fp8(float a) {       // encode -> byte
#if HW_FP8
    return __builtin_amdgcn_cvt_pk_fp8_f32(a, a, 0u, false) & 0xffu;
#else
    return sw_enc8(a);
#endif
}
// pack 4 floats -> 4 fp8 bytes in a uint
__device__ __forceinline__ unsigned pack4_fp8(float a, float b, float c, float d) {
#if HW_FP8
    unsigned u = __builtin_amdgcn_cvt_pk_fp8_f32(a, b, 0u, false);
    u = __builtin_amdgcn_cvt_pk_fp8_f32(c, d, u, true);
    return u;
#else
    return sw_enc8(a) | (sw_enc8(b) << 8) | (sw_enc8(c) << 16) | (sw_enc8(d) << 24);
#endif
}

// init: gcursor[b] = b*BCAP (fixed-capacity bucket bases), zero sums/cnt
__global__ __launch_bounds__(256) void k_init(int* __restrict__ gcursor,
                                              float* __restrict__ sums) {
    const int i = blockIdx.x * blockDim.x + threadIdx.x;
    if (i < NB) gcursor[i] = i * BCAP;
    if (i < NG * HH2 + NG) sums[i] = 0.f;
}

// LDS-binned scatter of packed (src<<9 | dstlocal) into fixed-capacity bucket streams.
// 256 buckets -> per-block per-bucket runs of ~32 entries (128B): coalesced-ish stores.
__global__ __launch_bounds__(256) void k_bscatter(const int* __restrict__ src,
                                                  const int* __restrict__ dst,
                                                  int* __restrict__ gcursor,
                                                  unsigned* __restrict__ pairs, int E) {
    __shared__ int cnt[NB];
    __shared__ int cur[NB];
    const int t = threadIdx.x;
    cnt[t] = 0;
    __syncthreads();
    const int base = blockIdx.x * EPB;
#pragma unroll
    for (int i = 0; i < EPB / 1024; ++i) {
        const int e = base + i * 1024 + t * 4;
        if (e < E) {
            const int4 d = *(const int4*)&dst[e];
            atomicAdd(&cnt[(unsigned)d.x / NPB], 1);
            atomicAdd(&cnt[(unsigned)d.y / NPB], 1);
            atomicAdd(&cnt[(unsigned)d.z / NPB], 1);
            atomicAdd(&cnt[(unsigned)d.w / NPB], 1);
        }
    }
    __syncthreads();
    {
        const int c = cnt[t];
        if (c) cur[t] = atomicAdd(&gcursor[t], c);
    }
    __syncthreads();
#pragma unroll
    for (int i = 0; i < EPB / 1024; ++i) {
        const int e = base + i * 1024 + t * 4;
        if (e < E) {
            const int4 d = *(const int4*)&dst[e];
            const int4 s = *(const int4*)&src[e];
            int p; unsigned bk, lo;
            bk = (unsigned)d.x / NPB; lo = d.x - bk * NPB;
            p = atomicAdd(&cur[bk], 1); pairs[p] = ((unsigned)s.x << 9) | lo;
            bk = (unsigned)d.y / NPB; lo = d.y - bk * NPB;
            p = atomicAdd(&cur[bk], 1); pairs[p] = ((unsigned)s.y << 9) | lo;
            bk = (unsigned)d.z / NPB; lo = d.z - bk * NPB;
            p = atomicAdd(&cur[bk], 1); pairs[p] = ((unsigned)s.z << 9) | lo;
            bk = (unsigned)d.w / NPB; lo = d.w - bk * NPB;
            p = atomicAdd(&cur[bk], 1); pairs[p] = ((unsigned)s.w << 9) | lo;
        }
    }
}

// per-bucket CSR finalize. One 512-thread block per bucket; ebeg = b*BCAP, eend = gcursor[b].
// Row starts 4-ALIGNED (degrees padded to mult-of-4; gaps unread).
__global__ __launch_bounds__(512) void k_csr(const unsigned* __restrict__ pairs,
                                             const int* __restrict__ gcursor,
                                             int* __restrict__ row_start,
                                             int* __restrict__ rend,
                                             float* __restrict__ dinv,
                                             int* __restrict__ esrc) {
    const int b = blockIdx.x;
    const int node0 = b * NPB;
    if (node0 >= NN) return;
    const int nn = min(NPB, NN - node0);
    __shared__ int cnt[NPB];
    __shared__ int scn[512];
    __shared__ int cur[NPB];
    const int t = threadIdx.x;
    if (t < NPB) cnt[t] = 0;
    __syncthreads();
    const int ebeg = b * BCAP, eend = gcursor[b];
    for (int j = ebeg + t; j < eend; j += 512)
        atomicAdd(&cnt[pairs[j] & 511u], 1);
    __syncthreads();
    const int v = (t < nn) ? cnt[t] : 0;
    const int pv = (v + 3) & ~3;
    scn[t] = pv;
    __syncthreads();
    for (int off = 1; off < 512; off <<= 1) {
        const int x = (t >= off) ? scn[t - off] : 0;
        __syncthreads();
        scn[t] += x;
        __syncthreads();
    }
    if (t < nn) {
        const int rs = ebeg + scn[t] - pv;   // 4-aligned
        row_start[node0 + t] = rs;
        rend[node0 + t]      = rs + v;
        cur[t] = rs;
        dinv[node0 + t] = rsqrtf((float)v + 1.f);
    }
    __syncthreads();
    for (int j = ebeg + t; j < eend; j += 512) {
        const unsigned p = pairs[j];
        const int pos = atomicAdd(&cur[p & 511u], 1);
        esrc[pos] = (int)(p >> 9);
    }
}

// BF16 MFMA GEMM: C[M,BN] = A[M,128] @ B[128,BN]; epilogue scale-by-dinv + fp8 store.
// A fragments loaded DIRECTLY from global (no LDS); B staged in LDS (bf16, swizzled).
template <int BN, bool ABF16>
__global__ __launch_bounds__(256) void k_mfma(const void* __restrict__ Ain,
                                              const float* __restrict__ Bin,
                                              unsigned char* __restrict__ Cout,
                                              const float* __restrict__ rowscale,
                                              int M) {
    __shared__ unsigned short Bs[BN][128];
    const int t = threadIdx.x;
    const int row0 = blockIdx.x * 128;

    // ---- stage B (whole 128-K, transposed, f32 -> bf16, swizzled) ----
    {
        constexpr int KSEG = (BN == 128) ? 64 : 32;
        const int n  = t & (BN - 1);
        const int kb = (t / BN) * KSEG;
#pragma unroll
        for (int i = 0; i < KSEG; i += 2) {
            const int k = kb + i;
            const unsigned u = pack2(Bin[(size_t)k * BN + n], Bin[(size_t)(k + 1) * BN + n]);
            *(unsigned*)&Bs[n][(((k >> 3) ^ (n & 7)) << 3) + (k & 7)] = u;
        }
    }

    const int lane = t & 63, wave = t >> 6;
    const int lr = lane & 15, lg = lane >> 4;
    constexpr int MR = 2;
    constexpr int NR = BN / 16;          // 8 (BN=128) or 4 (BN=64)
    const int wrow = wave * 32;

    // ---- A fragments direct from global (rows >= M clamped; outputs masked) ----
    bf16x8 afrag[4][MR];
#pragma unroll
    for (int m = 0; m < MR; ++m) {
        int row = row0 + wrow + m * 16 + lr;
        row = (row < M) ? row : (M - 1);
        if (ABF16) {
            const uint4* ap = (const uint4*)((const unsigned short*)Ain + (size_t)row * 128);
#pragma unroll
            for (int ks = 0; ks < 4; ++ks) {
                const uint4 v = ap[ks * 4 + lg];
                afrag[ks][m] = *(const bf16x8*)&v;
            }
        } else {
            const float* ap = (const float*)Ain + (size_t)row * 128;
#pragma unroll
            for (int ks = 0; ks < 4; ++ks) {
                const float4 f0 = *(const float4*)(ap + ks * 32 + lg * 8);
                const float4 f1 = *(const float4*)(ap + ks * 32 + lg * 8 + 4);
                const uint4 v = make_uint4(pack2(f0.x, f0.y), pack2(f0.z, f0.w),
                                           pack2(f1.x, f1.y), pack2(f1.z, f1.w));
                afrag[ks][m] = *(const bf16x8*)&v;
            }
        }
    }
    __syncthreads();

    // ---- MFMA ----
    f32x4 acc[MR][NR];
#pragma unroll
    for (int m = 0; m < MR; ++m)
#pragma unroll
        for (int n = 0; n < NR; ++n) acc[m][n] = (f32x4){0.f, 0.f, 0.f, 0.f};

#pragma unroll
    for (int ks = 0; ks < 4; ++ks) {
        const int cc = ((ks * 4 + lg) ^ (lr & 7)) * 8;
        bf16x8 b[NR];
#pragma unroll
        for (int n = 0; n < NR; ++n) b[n] = *(const bf16x8*)&Bs[n * 16 + lr][cc];
#pragma unroll
        for (int m = 0; m < MR; ++m)
#pragma unroll
            for (int n = 0; n < NR; ++n)
                acc[m][n] = __builtin_amdgcn_mfma_f32_16x16x32_bf16(afrag[ks][m], b[n], acc[m][n], 0, 0, 0);
    }

    // ---- epilogue: scale by dinv[row], fp8 store ----
#pragma unroll
    for (int m = 0; m < MR; ++m) {
        const int rb = wrow + m * 16 + lg * 4;
        float s[4]; int gr[4];
#pragma unroll
        for (int j = 0; j < 4; ++j) {
            gr[j] = row0 + rb + j;
            s[j] = (gr[j] < M) ? rowscale[gr[j]] : 0.f;
        }
#pragma unroll
        for (int n = 0; n < NR; ++n) {
            const int col = n * 16 + lr;
#pragma unroll
            for (int j = 0; j < 4; ++j)
                if (gr[j] < M)
                    Cout[(size_t)gr[j] * BN + col] = (unsigned char)f32_fp8(acc[m][n][j] * s[j]);
        }
    }
}

// layer-1 aggregation: one wave/node. Row = 16 uint2 (128 fp8). Quarter-wave per edge;
// main loop loads 16 indices as ONE int4 per lane (row starts 4-aligned).
__global__ __launch_bounds__(256) void k_agg1(const int* __restrict__ row_start,
                                              const int* __restrict__ row_end,
                                              const int* __restrict__ esrc,
                                              const float* __restrict__ dinv,
                                              const uint2* __restrict__ hb,
                                              const float* __restrict__ b,
                                              uint4* __restrict__ outp, int n) {
    const int wid  = (blockIdx.x * blockDim.x + threadIdx.x) >> 6;
    const int lane = threadIdx.x & 63;
    if (wid >= n) return;
    const int q  = lane >> 4;             // 0..3 edge slot
    const int ql = lane & 15;             // uint2 index within row
    const int beg = row_start[wid], end = row_end[wid];

    f32x4 accA = (f32x4){0.f, 0.f, 0.f, 0.f};
    f32x4 accB = accA;
    if (q == 0) {                         // self row once
        const uint2 u = hb[(size_t)wid * 16 + ql];
        accA = fp8x4_f32(u.x);
        accB = fp8x4_f32(u.y);
    }

    int j = beg;
    for (; j + 16 <= end; j += 16) {
        const int4 ix = *(const int4*)&esrc[j + q * 4];   // 16B-aligned (beg mult of 4)
        const uint2 u0 = hb[(size_t)ix.x * 16 + ql];
        const uint2 u1 = hb[(size_t)ix.y * 16 + ql];
        const uint2 u2 = hb[(size_t)ix.z * 16 + ql];
        const uint2 u3 = hb[(size_t)ix.w * 16 + ql];
        accA += (fp8x4_f32(u0.x) + fp8x4_f32(u1.x)) + (fp8x4_f32(u2.x) + fp8x4_f32(u3.x));
        accB += (fp8x4_f32(u0.y) + fp8x4_f32(u1.y)) + (fp8x4_f32(u2.y) + fp8x4_f32(u3.y));
    }
    for (; j + 4 <= end; j += 4) {
        const uint2 u = hb[(size_t)esrc[j + q] * 16 + ql];
        accA += fp8x4_f32(u.x);
        accB += fp8x4_f32(u.y);
    }
    if (j + q < end) {
        const uint2 u = hb[(size_t)esrc[j + q] * 16 + ql];
        accA += fp8x4_f32(u.x);
        accB += fp8x4_f32(u.y);
    }

    // combine quarter-wave partials
#pragma unroll
    for (int k = 0; k < 4; ++k) {
        accA[k] += __shfl_xor(accA[k], 16); accA[k] += __shfl_xor(accA[k], 32);
        accB[k] += __shfl_xor(accB[k], 16); accB[k] += __shfl_xor(accB[k], 32);
    }

    if (q == 0) {
        const float dd = dinv[wid];
        const float4 bv0 = *(const float4*)&b[ql * 8];
        const float4 bv1 = *(const float4*)&b[ql * 8 + 4];
        float r[8];
        r[0] = fmaxf(fmaf(dd, accA[0], bv0.x), 0.f);
        r[1] = fmaxf(fmaf(dd, accA[1], bv0.y), 0.f);
        r[2] = fmaxf(fmaf(dd, accA[2], bv0.z), 0.f);
        r[3] = fmaxf(fmaf(dd, accA[3], bv0.w), 0.f);
        r[4] = fmaxf(fmaf(dd, accB[0], bv1.x), 0.f);
        r[5] = fmaxf(fmaf(dd, accB[1], bv1.y), 0.f);
        r[6] = fmaxf(fmaf(dd, accB[2], bv1.z), 0.f);
        r[7] = fmaxf(fmaf(dd, accB[3], bv1.w), 0.f);
        outp[(size_t)wid * 16 + ql] = make_uint4(pack2(r[0], r[1]), pack2(r[2], r[3]),
                                                 pack2(r[4], r[5]), pack2(r[6], r[7]));
    }
}

// layer-2 aggregation: one wave/node. Row = 8 uint2 (64 fp8). Eighth-wave per edge;
// main loop loads 16 indices as ONE int2 per lane. Output fp8.
__global__ __launch_bounds__(256) void k_agg2(const int* __restrict__ row_start,
                                              const int* __restrict__ row_end,
                                              const int* __restrict__ esrc,
                                              const float* __restrict__ dinv,
                                              const uint2* __restrict__ hb,
                                              const float* __restrict__ b,
                                              uint2* __restrict__ outp, int n) {
    const int wid  = (blockIdx.x * blockDim.x + threadIdx.x) >> 6;
    const int lane = threadIdx.x & 63;
    if (wid >= n) return;
    const int o  = lane >> 3;             // 0..7 edge slot
    const int ol = lane & 7;              // uint2 index within row
    const int beg = row_start[wid], end = row_end[wid];

    f32x4 accA = (f32x4){0.f, 0.f, 0.f, 0.f};
    f32x4 accB = accA;
    if (o == 0) {                         // self row once
        const uint2 u = hb[(size_t)wid * 8 + ol];
        accA = fp8x4_f32(u.x);
        accB = fp8x4_f32(u.y);
    }

    int j = beg;
    for (; j + 16 <= end; j += 16) {
        const int2 ix = *(const int2*)&esrc[j + o * 2];   // 8B-aligned
        const uint2 u0 = hb[(size_t)ix.x * 8 + ol];
        const uint2 u1 = hb[(size_t)ix.y * 8 + ol];
        accA += fp8x4_f32(u0.x) + fp8x4_f32(u1.x);
        accB += fp8x4_f32(u0.y) + fp8x4_f32(u1.y);
    }
    for (; j + 8 <= end; j += 8) {
        const uint2 u = hb[(size_t)esrc[j + o] * 8 + ol];
        accA += fp8x4_f32(u.x);
        accB += fp8x4_f32(u.y);
    }
    if (j + o < end) {
        const uint2 u = hb[(size_t)esrc[j + o] * 8 + ol];
        accA += fp8x4_f32(u.x);
        accB += fp8x4_f32(u.y);
    }

    // combine eighth-wave partials
#pragma unroll
    for (int k = 0; k < 4; ++k) {
        accA[k] += __shfl_xor(accA[k], 8);
        accA[k] += __shfl_xor(accA[k], 16);
        accA[k] += __shfl_xor(accA[k], 32);
        accB[k] += __shfl_xor(accB[k], 8);
        accB[k] += __shfl_xor(accB[k], 16);
        accB[k] += __shfl_xor(accB[k], 32);
    }

    if (o == 0) {
        const float dd = dinv[wid];
        const float4 bv0 = *(const float4*)&b[ol * 8];
        const float4 bv1 = *(const float4*)&b[ol * 8 + 4];
        const unsigned w0 = pack4_fp8(fmaf(dd, accA[0], bv0.x), fmaf(dd, accA[1], bv0.y),
                                      fmaf(dd, accA[2], bv0.z), fmaf(dd, accA[3], bv0.w));
        const unsigned w1 = pack4_fp8(fmaf(dd, accB[0], bv1.x), fmaf(dd, accB[1], bv1.y),
                                      fmaf(dd, accB[2], bv1.z), fmaf(dd, accB[3], bv1.w));
        outp[(size_t)wid * 8 + ol] = make_uint2(w0, w1);
    }
}

// mean-pool: one wave per 128 consecutive nodes (batch sorted), lane = feature (fp8 in)
__global__ __launch_bounds__(256) void k_pool(const unsigned char* __restrict__ v2,
                                              const int* __restrict__ batch,
                                              float* __restrict__ sums,
                                              float* __restrict__ cnt, int n) {
    constexpr int NPW = 128;
    const int gt = blockIdx.x * blockDim.x + threadIdx.x;
    const int wave = gt >> 6;
    const int lane = threadIdx.x & 63;
    const int start = wave * NPW;
    if (start >= n) return;
    const int end = min(start + NPW, n);
    float acc = 0.f, cacc = 0.f;
    int cur = batch[start];
    for (int nd = start; nd < end; ++nd) {
        const int gid = batch[nd];
        if (gid != cur) {
            atomicAdd(&sums[cur * HH2 + lane], acc);
            if (lane == 0) atomicAdd(&cnt[cur], cacc);
            acc = 0.f; cacc = 0.f; cur = gid;
        }
        acc += fp8_f32(v2[(size_t)nd * 64 + lane]);
        cacc += 1.f;
    }
    atomicAdd(&sums[cur * HH2 + lane], acc);
    if (lane == 0) atomicAdd(&cnt[cur], cacc);
}

__global__ void k_fc(const float* __restrict__ sums, const float* __restrict__ cnt,
                     const float* __restrict__ Wfc, const float* __restrict__ bfc,
                     float* __restrict__ out) {
    const int tid = threadIdx.x;
    if (tid >= NG * NC) return;
    const int g = tid / NC;
    const int c = tid % NC;
    float a = 0.f;
    for (int k = 0; k < HH2; ++k)
        a = fmaf(sums[g * HH2 + k], Wfc[k * NC + c], a);
    const float cg = fmaxf(cnt[g], 1.0f);
    out[g * NC + c] = a / cg + bfc[c];
}

extern "C" void kernel_launch(void* const* d_in, const int* in_sizes, int n_in,
                              void* d_out, int out_size, void* d_ws, size_t ws_size,
                              hipStream_t stream) {
    const float* x   = (const float*)d_in[0];
    const int*   ei  = (const int*)d_in[1];
    const int*   bat = (const int*)d_in[2];
    const float* W1  = (const float*)d_in[3];
    const float* b1  = (const float*)d_in[4];
    const float* W2  = (const float*)d_in[5];
    const float* b2  = (const float*)d_in[6];
    const float* Wfc = (const float*)d_in[7];
    const float* bfc = (const float*)d_in[8];
    float* out = (float*)d_out;

    const int* src = ei;
    const int* dst = ei + NE;

    // workspace layout (float/u32 slots):
    // [0, N*64)                relu1 (uint, bf16 pairs) — later v2 (fp8 N*64 B) reuses
    // [N*64, N*96)             h1b fp8 (N*128 B) — later h2b fp8 (N*64 B) reuses
    // [N*96, N*97)             dinv
    // [N*97, N*98)             row_start
    // [N*98, N*99)             rend
    // [N*99, +NB*BCAP)         esrc  (fixed-capacity bucketed, 4-aligned rows)
    // [.., +NB*BCAP)           pairs (fixed-capacity bucketed)
    // then sums, cnt, gcursor
    float* ws = (float*)d_ws;
    unsigned* relu1     = (unsigned*)ws;
    unsigned char* v2   = (unsigned char*)ws;
    unsigned char* h1b  = (unsigned char*)(ws + (size_t)NN * 64);
    unsigned char* h2b  = (unsigned char*)(ws + (size_t)NN * 64);
    float*    dinv      = ws + (size_t)NN * 96;
    int*      row_start = (int*)(ws + (size_t)NN * 97);
    int*      rend      = (int*)(ws + (size_t)NN * 98);
    int*      esrc      = (int*)(ws + (size_t)NN * 99);
    unsigned* pairs     = (unsigned*)(ws + (size_t)NN * 99 + (size_t)NB * BCAP);
    float*    sums      = ws + (size_t)NN * 99 + 2 * (size_t)NB * BCAP;
    float*    cntf      = sums + NG * HH2;
    int*      gcursor   = (int*)(cntf + NG);   // NB entries

    // ---- init + bucketed CSR build (fixed-capacity buckets, no count/scan passes) ----
    k_init<<<(NG * HH2 + NG + 255) / 256, 256, 0, stream>>>(gcursor, sums);
    k_bscatter<<<NBLK_B, 256, 0, stream>>>(src, dst, gcursor, pairs, NE);
    k_csr<<<NB, 512, 0, stream>>>(pairs, gcursor, row_start, rend, dinv, esrc);

    const int gblk = (NN + 127) / 128;   // 782

    // ---- layer 1: h1b = fp8(dinv[row] * (x @ W1)) via MFMA ----
    k_mfma<128, false><<<gblk, 256, 0, stream>>>(x, W1, h1b, dinv, NN);
    k_agg1<<<(NN * 64 + 255) / 256, 256, 0, stream>>>(row_start, rend, esrc, dinv,
                                                      (const uint2*)h1b, b1,
                                                      (uint4*)relu1, NN);

    // ---- layer 2: h2b = fp8(dinv[row] * (relu1 @ W2)) via MFMA ----
    k_mfma<64, true><<<gblk, 256, 0, stream>>>(relu1, W2, h2b, dinv, NN);
    k_agg2<<<(NN * 64 + 255) / 256, 256, 0, stream>>>(row_start, rend, esrc, dinv,
                                                      (const uint2*)h2b, b2,
                                                      (uint2*)v2, NN);

    // ---- pool ----
    {
        const int waves = (NN + 127) / 128;
        const int blocks = (waves * 64 + 255) / 256;
        k_pool<<<blocks, 256, 0, stream>>>(v2, bat, sums, cntf, NN);
    }

    // ---- final FC ----
    k_fc<<<1, 640, 0, stream>>>(sums, cntf, Wfc, bfc, out);
}

// Round 15
// 219.830 us; speedup vs baseline: 1.0547x; 1.0164x over previous
//
#include <hip/hip_runtime.h>
#include <cstdint>

#define NN   100000
#define NE   1600000
#define FIN  128
#define HH1  128
#define HH2  64
#define NC   10
#define NG   64

#define NB   256           // buckets
#define NPB  392           // nodes per bucket (256*392 >= 100000)
#define BCAP 8192          // fixed per-bucket capacity (max padded bucket ~7750)
#define EPS  4096          // edges per scatter block
#define NBLK_B ((NE + EPS - 1) / EPS)   // 391

typedef __attribute__((ext_vector_type(8))) short bf16x8;
typedef __attribute__((ext_vector_type(4))) float f32x4;
typedef __attribute__((ext_vector_type(2))) float f32x2;

#if defined(__has_builtin)
#  if __has_builtin(__builtin_amdgcn_cvt_pk_f32_fp8) && \
      __has_builtin(__builtin_amdgcn_cvt_f32_fp8) && \
      __has_builtin(__builtin_amdgcn_cvt_pk_fp8_f32)
#    define HW_FP8 1
#  endif
#endif
#ifndef HW_FP8
#  define HW_FP8 0
#endif

__device__ __forceinline__ unsigned pack2(float a, float b) {
    union { float f; unsigned u; } x, y; x.f = a; y.f = b;
    const unsigned lo = x.u + 0x7fffu + ((x.u >> 16) & 1u);
    const unsigned hi = y.u + 0x7fffu + ((y.u >> 16) & 1u);
    return (lo >> 16) | (hi & 0xffff0000u);
}

// ---- fp8 e4m3 encode/decode (HW converts when available; SW fallback is
// self-consistent, so correctness never depends on the HW format) ----
__device__ __forceinline__ float sw_dec8(unsigned b) {
    const unsigned s = b >> 7, e = (b >> 3) & 15u, m = b & 7u;
    float v;
    if (e == 0) v = (float)m * 0.001953125f;               // m * 2^-9
    else { union { unsigned u; float f; } y; y.u = ((e + 120u) << 23) | (m << 20); v = y.f; }
    return s ? -v : v;
}
__device__ __forceinline__ unsigned sw_enc8(float f) {
    union { float f; unsigned u; } x; x.f = f;
    const unsigned s = (x.u >> 31) << 7;
    float a = fabsf(f);
    a = fminf(a, 448.0f);
    unsigned ia;
    if (a < 0.015625f) {
        ia = (unsigned)(int)rintf(a * 512.0f);
    } else {
        union { float f; unsigned u; } y; y.f = a;
        int e = (int)((y.u >> 23) & 255u) - 127;
        unsigned keep = (y.u >> 20) & 7u;
        const unsigned rest = y.u & 0xfffffu;
        keep += (rest > 0x80000u) || (rest == 0x80000u && (keep & 1u));
        if (keep == 8u) { keep = 0u; e += 1; }
        if (e >= 8) { e = 8; if (keep > 6u) keep = 6u; }
        ia = ((unsigned)(e + 7) << 3) | keep;
    }
    return s | ia;
}
// decode 4 fp8 bytes of a uint -> 4 floats
__device__ __forceinline__ f32x4 fp8x4_f32(unsigned u) {
#if HW_FP8
    f32x2 lo = __builtin_amdgcn_cvt_pk_f32_fp8(u, false);
    f32x2 hi = __builtin_amdgcn_cvt_pk_f32_fp8(u, true);
    return (f32x4){lo[0], lo[1], hi[0], hi[1]};
#else
    return (f32x4){sw_dec8(u & 0xffu), sw_dec8((u >> 8) & 0xffu),
                   sw_dec8((u >> 16) & 0xffu), sw_dec8(u >> 24)};
#endif
}
__device__ __forceinline__ float fp8_f32(unsigned b) {       // decode byte 0
#if HW_FP8
    return __builtin_amdgcn_cvt_f32_fp8(b, 0);
#else
    return sw_dec8(b & 0xffu);
#endif
}
__device__ __forceinline__ unsigned f32_fp8(float a) {       // encode -> byte
#if HW_FP8
    return __builtin_amdgcn_cvt_pk_fp8_f32(a, a, 0u, false) & 0xffu;
#else
    return sw_enc8(a);
#endif
}
// pack 4 floats -> 4 fp8 bytes in a uint
__device__ __forceinline__ unsigned pack4_fp8(float a, float b, float c, float d) {
#if HW_FP8
    unsigned u = __builtin_amdgcn_cvt_pk_fp8_f32(a, b, 0u, false);
    u = __builtin_amdgcn_cvt_pk_fp8_f32(c, d, u, true);
    return u;
#else
    return sw_enc8(a) | (sw_enc8(b) << 8) | (sw_enc8(c) << 16) | (sw_enc8(d) << 24);
#endif
}

// init: gcursor[b] = b*BCAP (fixed-capacity bucket bases), zero sums/cnt
__global__ __launch_bounds__(256) void k_init(int* __restrict__ gcursor,
                                              float* __restrict__ sums) {
    const int i = blockIdx.x * blockDim.x + threadIdx.x;
    if (i < NB) gcursor[i] = i * BCAP;
    if (i < NG * HH2 + NG) sums[i] = 0.f;
}

// LDS counting-sort scatter: pack (src<<9 | dstlocal), sort 4096 edges by bucket in
// LDS, then COALESCED copy-out (consecutive threads -> consecutive addresses per run).
__global__ __launch_bounds__(256) void k_bscatter(const int* __restrict__ src,
                                                  const int* __restrict__ dst,
                                                  int* __restrict__ gcursor,
                                                  unsigned* __restrict__ pairs, int E) {
    __shared__ int cnt[NB];
    __shared__ int lst[NB];      // scan buffer -> exclusive starts
    __shared__ int bglob[NB];    // global dest base per bucket
    __shared__ unsigned buf[EPS];
    __shared__ int gd[EPS];
    const int t = threadIdx.x;
    cnt[t] = 0;
    __syncthreads();
    const int base = blockIdx.x * EPS;
    unsigned val[16]; int bo[16];
#pragma unroll
    for (int i = 0; i < 4; ++i) {
        const int e = base + i * 1024 + t * 4;
        if (e < E) {   // NE % 4 == 0, e % 4 == 0 -> int4 safe
            const int4 d = *(const int4*)&dst[e];
            const int4 s = *(const int4*)&src[e];
            unsigned bk;
            bk = (unsigned)d.x / NPB;
            val[i * 4 + 0] = ((unsigned)s.x << 9) | ((unsigned)d.x - bk * NPB);
            bo[i * 4 + 0] = (int)((bk << 16) | (unsigned)atomicAdd(&cnt[bk], 1));
            bk = (unsigned)d.y / NPB;
            val[i * 4 + 1] = ((unsigned)s.y << 9) | ((unsigned)d.y - bk * NPB);
            bo[i * 4 + 1] = (int)((bk << 16) | (unsigned)atomicAdd(&cnt[bk], 1));
            bk = (unsigned)d.z / NPB;
            val[i * 4 + 2] = ((unsigned)s.z << 9) | ((unsigned)d.z - bk * NPB);
            bo[i * 4 + 2] = (int)((bk << 16) | (unsigned)atomicAdd(&cnt[bk], 1));
            bk = (unsigned)d.w / NPB;
            val[i * 4 + 3] = ((unsigned)s.w << 9) | ((unsigned)d.w - bk * NPB);
            bo[i * 4 + 3] = (int)((bk << 16) | (unsigned)atomicAdd(&cnt[bk], 1));
        } else {
            bo[i * 4 + 0] = bo[i * 4 + 1] = bo[i * 4 + 2] = bo[i * 4 + 3] = -1;
        }
    }
    __syncthreads();
    // inclusive scan of counts (Hillis-Steele over 256)
    const int v = cnt[t];
    lst[t] = v;
    __syncthreads();
    for (int off = 1; off < 256; off <<= 1) {
        const int x = (t >= off) ? lst[t - off] : 0;
        __syncthreads();
        lst[t] += x;
        __syncthreads();
    }
    const int total = lst[NB - 1];
    const int excl = lst[t] - v;
    if (v > 0) bglob[t] = atomicAdd(&gcursor[t], v);
    __syncthreads();
    lst[t] = excl;               // convert to exclusive starts
    __syncthreads();
    // place into LDS-sorted buffer with precomputed global destinations
#pragma unroll
    for (int i = 0; i < 16; ++i) {
        if (bo[i] >= 0) {
            const int bk = bo[i] >> 16;
            const int r  = bo[i] & 0xffff;
            const int pos = lst[bk] + r;
            buf[pos] = val[i];
            gd[pos]  = bglob[bk] + r;
        }
    }
    __syncthreads();
    // coalesced copy-out
    for (int p = t; p < total; p += 256)
        pairs[gd[p]] = buf[p];
}

// per-bucket CSR finalize. One 512-thread block per bucket; ebeg = b*BCAP, eend = gcursor[b].
// Row starts 4-ALIGNED (degrees padded to mult-of-4; gaps unread).
__global__ __launch_bounds__(512) void k_csr(const unsigned* __restrict__ pairs,
                                             const int* __restrict__ gcursor,
                                             int* __restrict__ row_start,
                                             int* __restrict__ rend,
                                             float* __restrict__ dinv,
                                             int* __restrict__ esrc) {
    const int b = blockIdx.x;
    const int node0 = b * NPB;
    if (node0 >= NN) return;
    const int nn = min(NPB, NN - node0);
    __shared__ int cnt[NPB];
    __shared__ int scn[512];
    __shared__ int cur[NPB];
    const int t = threadIdx.x;
    if (t < NPB) cnt[t] = 0;
    __syncthreads();
    const int ebeg = b * BCAP, eend = gcursor[b];
    for (int j = ebeg + t; j < eend; j += 512)
        atomicAdd(&cnt[pairs[j] & 511u], 1);
    __syncthreads();
    const int v = (t < nn) ? cnt[t] : 0;
    const int pv = (v + 3) & ~3;
    scn[t] = pv;
    __syncthreads();
    for (int off = 1; off < 512; off <<= 1) {
        const int x = (t >= off) ? scn[t - off] : 0;
        __syncthreads();
        scn[t] += x;
        __syncthreads();
    }
    if (t < nn) {
        const int rs = ebeg + scn[t] - pv;   // 4-aligned
        row_start[node0 + t] = rs;
        rend[node0 + t]      = rs + v;
        cur[t] = rs;
        dinv[node0 + t] = rsqrtf((float)v + 1.f);
    }
    __syncthreads();
    for (int j = ebeg + t; j < eend; j += 512) {
        const unsigned p = pairs[j];
        const int pos = atomicAdd(&cur[p & 511u], 1);
        esrc[pos] = (int)(p >> 9);
    }
}

// BF16 MFMA GEMM: C[M,BN] = A[M,128] @ B[128,BN]; epilogue scale-by-dinv + fp8 store.
// A fragments loaded DIRECTLY from global (no LDS); B staged in LDS (bf16, swizzled).
template <int BN, bool ABF16>
__global__ __launch_bounds__(256) void k_mfma(const void* __restrict__ Ain,
                                              const float* __restrict__ Bin,
                                              unsigned char* __restrict__ Cout,
                                              const float* __restrict__ rowscale,
                                              int M) {
    __shared__ unsigned short Bs[BN][128];
    const int t = threadIdx.x;
    const int row0 = blockIdx.x * 128;

    // ---- stage B (whole 128-K, transposed, f32 -> bf16, swizzled) ----
    {
        constexpr int KSEG = (BN == 128) ? 64 : 32;
        const int n  = t & (BN - 1);
        const int kb = (t / BN) * KSEG;
#pragma unroll
        for (int i = 0; i < KSEG; i += 2) {
            const int k = kb + i;
            const unsigned u = pack2(Bin[(size_t)k * BN + n], Bin[(size_t)(k + 1) * BN + n]);
            *(unsigned*)&Bs[n][(((k >> 3) ^ (n & 7)) << 3) + (k & 7)] = u;
        }
    }

    const int lane = t & 63, wave = t >> 6;
    const int lr = lane & 15, lg = lane >> 4;
    constexpr int MR = 2;
    constexpr int NR = BN / 16;          // 8 (BN=128) or 4 (BN=64)
    const int wrow = wave * 32;

    // ---- A fragments direct from global (rows >= M clamped; outputs masked) ----
    bf16x8 afrag[4][MR];
#pragma unroll
    for (int m = 0; m < MR; ++m) {
        int row = row0 + wrow + m * 16 + lr;
        row = (row < M) ? row : (M - 1);
        if (ABF16) {
            const uint4* ap = (const uint4*)((const unsigned short*)Ain + (size_t)row * 128);
#pragma unroll
            for (int ks = 0; ks < 4; ++ks) {
                const uint4 v = ap[ks * 4 + lg];
                afrag[ks][m] = *(const bf16x8*)&v;
            }
        } else {
            const float* ap = (const float*)Ain + (size_t)row * 128;
#pragma unroll
            for (int ks = 0; ks < 4; ++ks) {
                const float4 f0 = *(const float4*)(ap + ks * 32 + lg * 8);
                const float4 f1 = *(const float4*)(ap + ks * 32 + lg * 8 + 4);
                const uint4 v = make_uint4(pack2(f0.x, f0.y), pack2(f0.z, f0.w),
                                           pack2(f1.x, f1.y), pack2(f1.z, f1.w));
                afrag[ks][m] = *(const bf16x8*)&v;
            }
        }
    }
    __syncthreads();

    // ---- MFMA ----
    f32x4 acc[MR][NR];
#pragma unroll
    for (int m = 0; m < MR; ++m)
#pragma unroll
        for (int n = 0; n < NR; ++n) acc[m][n] = (f32x4){0.f, 0.f, 0.f, 0.f};

#pragma unroll
    for (int ks = 0; ks < 4; ++ks) {
        const int cc = ((ks * 4 + lg) ^ (lr & 7)) * 8;
        bf16x8 b[NR];
#pragma unroll
        for (int n = 0; n < NR; ++n) b[n] = *(const bf16x8*)&Bs[n * 16 + lr][cc];
#pragma unroll
        for (int m = 0; m < MR; ++m)
#pragma unroll
            for (int n = 0; n < NR; ++n)
                acc[m][n] = __builtin_amdgcn_mfma_f32_16x16x32_bf16(afrag[ks][m], b[n], acc[m][n], 0, 0, 0);
    }

    // ---- epilogue: scale by dinv[row], fp8 store ----
#pragma unroll
    for (int m = 0; m < MR; ++m) {
        const int rb = wrow + m * 16 + lg * 4;
        float s[4]; int gr[4];
#pragma unroll
        for (int j = 0; j < 4; ++j) {
            gr[j] = row0 + rb + j;
            s[j] = (gr[j] < M) ? rowscale[gr[j]] : 0.f;
        }
#pragma unroll
        for (int n = 0; n < NR; ++n) {
            const int col = n * 16 + lr;
#pragma unroll
            for (int j = 0; j < 4; ++j)
                if (gr[j] < M)
                    Cout[(size_t)gr[j] * BN + col] = (unsigned char)f32_fp8(acc[m][n][j] * s[j]);
        }
    }
}

// layer-1 aggregation: one wave/node. Row = 16 uint2 (128 fp8). Quarter-wave per edge;
// main loop loads 16 indices as ONE int4 per lane (row starts 4-aligned).
__global__ __launch_bounds__(256) void k_agg1(const int* __restrict__ row_start,
                                              const int* __restrict__ row_end,
                                              const int* __restrict__ esrc,
                                              const float* __restrict__ dinv,
                                              const uint2* __restrict__ hb,
                                              const float* __restrict__ b,
                                              uint4* __restrict__ outp, int n) {
    const int wid  = (blockIdx.x * blockDim.x + threadIdx.x) >> 6;
    const int lane = threadIdx.x & 63;
    if (wid >= n) return;
    const int q  = lane >> 4;             // 0..3 edge slot
    const int ql = lane & 15;             // uint2 index within row
    const int beg = row_start[wid], end = row_end[wid];

    f32x4 accA = (f32x4){0.f, 0.f, 0.f, 0.f};
    f32x4 accB = accA;
    if (q == 0) {                         // self row once
        const uint2 u = hb[(size_t)wid * 16 + ql];
        accA = fp8x4_f32(u.x);
        accB = fp8x4_f32(u.y);
    }

    int j = beg;
    for (; j + 16 <= end; j += 16) {
        const int4 ix = *(const int4*)&esrc[j + q * 4];   // 16B-aligned (beg mult of 4)
        const uint2 u0 = hb[(size_t)ix.x * 16 + ql];
        const uint2 u1 = hb[(size_t)ix.y * 16 + ql];
        const uint2 u2 = hb[(size_t)ix.z * 16 + ql];
        const uint2 u3 = hb[(size_t)ix.w * 16 + ql];
        accA += (fp8x4_f32(u0.x) + fp8x4_f32(u1.x)) + (fp8x4_f32(u2.x) + fp8x4_f32(u3.x));
        accB += (fp8x4_f32(u0.y) + fp8x4_f32(u1.y)) + (fp8x4_f32(u2.y) + fp8x4_f32(u3.y));
    }
    for (; j + 4 <= end; j += 4) {
        const uint2 u = hb[(size_t)esrc[j + q] * 16 + ql];
        accA += fp8x4_f32(u.x);
        accB += fp8x4_f32(u.y);
    }
    if (j + q < end) {
        const uint2 u = hb[(size_t)esrc[j + q] * 16 + ql];
        accA += fp8x4_f32(u.x);
        accB += fp8x4_f32(u.y);
    }

    // combine quarter-wave partials
#pragma unroll
    for (int k = 0; k < 4; ++k) {
        accA[k] += __shfl_xor(accA[k], 16); accA[k] += __shfl_xor(accA[k], 32);
        accB[k] += __shfl_xor(accB[k], 16); accB[k] += __shfl_xor(accB[k], 32);
    }

    if (q == 0) {
        const float dd = dinv[wid];
        const float4 bv0 = *(const float4*)&b[ql * 8];
        const float4 bv1 = *(const float4*)&b[ql * 8 + 4];
        float r[8];
        r[0] = fmaxf(fmaf(dd, accA[0], bv0.x), 0.f);
        r[1] = fmaxf(fmaf(dd, accA[1], bv0.y), 0.f);
        r[2] = fmaxf(fmaf(dd, accA[2], bv0.z), 0.f);
        r[3] = fmaxf(fmaf(dd, accA[3], bv0.w), 0.f);
        r[4] = fmaxf(fmaf(dd, accB[0], bv1.x), 0.f);
        r[5] = fmaxf(fmaf(dd, accB[1], bv1.y), 0.f);
        r[6] = fmaxf(fmaf(dd, accB[2], bv1.z), 0.f);
        r[7] = fmaxf(fmaf(dd, accB[3], bv1.w), 0.f);
        outp[(size_t)wid * 16 + ql] = make_uint4(pack2(r[0], r[1]), pack2(r[2], r[3]),
                                                 pack2(r[4], r[5]), pack2(r[6], r[7]));
    }
}

// layer-2 aggregation: one wave/node. Row = 8 uint2 (64 fp8). Eighth-wave per edge;
// main loop loads 16 indices as ONE int2 per lane. Output fp8.
__global__ __launch_bounds__(256) void k_agg2(const int* __restrict__ row_start,
                                              const int* __restrict__ row_end,
                                              const int* __restrict__ esrc,
                                              const float* __restrict__ dinv,
                                              const uint2* __restrict__ hb,
                                              const float* __restrict__ b,
                                              uint2* __restrict__ outp, int n) {
    const int wid  = (blockIdx.x * blockDim.x + threadIdx.x) >> 6;
    const int lane = threadIdx.x & 63;
    if (wid >= n) return;
    const int o  = lane >> 3;             // 0..7 edge slot
    const int ol = lane & 7;              // uint2 index within row
    const int beg = row_start[wid], end = row_end[wid];

    f32x4 accA = (f32x4){0.f, 0.f, 0.f, 0.f};
    f32x4 accB = accA;
    if (o == 0) {                         // self row once
        const uint2 u = hb[(size_t)wid * 8 + ol];
        accA = fp8x4_f32(u.x);
        accB = fp8x4_f32(u.y);
    }

    int j = beg;
    for (; j + 16 <= end; j += 16) {
        const int2 ix = *(const int2*)&esrc[j + o * 2];   // 8B-aligned
        const uint2 u0 = hb[(size_t)ix.x * 8 + ol];
        const uint2 u1 = hb[(size_t)ix.y * 8 + ol];
        accA += fp8x4_f32(u0.x) + fp8x4_f32(u1.x);
        accB += fp8x4_f32(u0.y) + fp8x4_f32(u1.y);
    }
    for (; j + 8 <= end; j += 8) {
        const uint2 u = hb[(size_t)esrc[j + o] * 8 + ol];
        accA += fp8x4_f32(u.x);
        accB += fp8x4_f32(u.y);
    }
    if (j + o < end) {
        const uint2 u = hb[(size_t)esrc[j + o] * 8 + ol];
        accA += fp8x4_f32(u.x);
        accB += fp8x4_f32(u.y);
    }

    // combine eighth-wave partials
#pragma unroll
    for (int k = 0; k < 4; ++k) {
        accA[k] += __shfl_xor(accA[k], 8);
        accA[k] += __shfl_xor(accA[k], 16);
        accA[k] += __shfl_xor(accA[k], 32);
        accB[k] += __shfl_xor(accB[k], 8);
        accB[k] += __shfl_xor(accB[k], 16);
        accB[k] += __shfl_xor(accB[k], 32);
    }

    if (o == 0) {
        const float dd = dinv[wid];
        const float4 bv0 = *(const float4*)&b[ol * 8];
        const float4 bv1 = *(const float4*)&b[ol * 8 + 4];
        const unsigned w0 = pack4_fp8(fmaf(dd, accA[0], bv0.x), fmaf(dd, accA[1], bv0.y),
                                      fmaf(dd, accA[2], bv0.z), fmaf(dd, accA[3], bv0.w));
        const unsigned w1 = pack4_fp8(fmaf(dd, accB[0], bv1.x), fmaf(dd, accB[1], bv1.y),
                                      fmaf(dd, accB[2], bv1.z), fmaf(dd, accB[3], bv1.w));
        outp[(size_t)wid * 8 + ol] = make_uint2(w0, w1);
    }
}

// mean-pool: one wave per 128 consecutive nodes (batch sorted), lane = feature (fp8 in)
__global__ __launch_bounds__(256) void k_pool(const unsigned char* __restrict__ v2,
                                              const int* __restrict__ batch,
                                              float* __restrict__ sums,
                                              float* __restrict__ cnt, int n) {
    constexpr int NPW = 128;
    const int gt = blockIdx.x * blockDim.x + threadIdx.x;
    const int wave = gt >> 6;
    const int lane = threadIdx.x & 63;
    const int start = wave * NPW;
    if (start >= n) return;
    const int end = min(start + NPW, n);
    float acc = 0.f, cacc = 0.f;
    int cur = batch[start];
    for (int nd = start; nd < end; ++nd) {
        const int gid = batch[nd];
        if (gid != cur) {
            atomicAdd(&sums[cur * HH2 + lane], acc);
            if (lane == 0) atomicAdd(&cnt[cur], cacc);
            acc = 0.f; cacc = 0.f; cur = gid;
        }
        acc += fp8_f32(v2[(size_t)nd * 64 + lane]);
        cacc += 1.f;
    }
    atomicAdd(&sums[cur * HH2 + lane], acc);
    if (lane == 0) atomicAdd(&cnt[cur], cacc);
}

__global__ void k_fc(const float* __restrict__ sums, const float* __restrict__ cnt,
                     const float* __restrict__ Wfc, const float* __restrict__ bfc,
                     float* __restrict__ out) {
    const int tid = threadIdx.x;
    if (tid >= NG * NC) return;
    const int g = tid / NC;
    const int c = tid % NC;
    float a = 0.f;
    for (int k = 0; k < HH2; ++k)
        a = fmaf(sums[g * HH2 + k], Wfc[k * NC + c], a);
    const float cg = fmaxf(cnt[g], 1.0f);
    out[g * NC + c] = a / cg + bfc[c];
}

extern "C" void kernel_launch(void* const* d_in, const int* in_sizes, int n_in,
                              void* d_out, int out_size, void* d_ws, size_t ws_size,
                              hipStream_t stream) {
    const float* x   = (const float*)d_in[0];
    const int*   ei  = (const int*)d_in[1];
    const int*   bat = (const int*)d_in[2];
    const float* W1  = (const float*)d_in[3];
    const float* b1  = (const float*)d_in[4];
    const float* W2  = (const float*)d_in[5];
    const float* b2  = (const float*)d_in[6];
    const float* Wfc = (const float*)d_in[7];
    const float* bfc = (const float*)d_in[8];
    float* out = (float*)d_out;

    const int* src = ei;
    const int* dst = ei + NE;

    // workspace layout (float/u32 slots):
    // [0, N*64)                relu1 (uint, bf16 pairs) — later v2 (fp8 N*64 B) reuses
    // [N*64, N*96)             h1b fp8 (N*128 B) — later h2b fp8 (N*64 B) reuses
    // [N*96, N*97)             dinv
    // [N*97, N*98)             row_start
    // [N*98, N*99)             rend
    // [N*99, +NB*BCAP)         esrc  (fixed-capacity bucketed, 4-aligned rows)
    // [.., +NB*BCAP)           pairs (fixed-capacity bucketed)
    // then sums, cnt, gcursor
    float* ws = (float*)d_ws;
    unsigned* relu1     = (unsigned*)ws;
    unsigned char* v2   = (unsigned char*)ws;
    unsigned char* h1b  = (unsigned char*)(ws + (size_t)NN * 64);
    unsigned char* h2b  = (unsigned char*)(ws + (size_t)NN * 64);
    float*    dinv      = ws + (size_t)NN * 96;
    int*      row_start = (int*)(ws + (size_t)NN * 97);
    int*      rend      = (int*)(ws + (size_t)NN * 98);
    int*      esrc      = (int*)(ws + (size_t)NN * 99);
    unsigned* pairs     = (unsigned*)(ws + (size_t)NN * 99 + (size_t)NB * BCAP);
    float*    sums      = ws + (size_t)NN * 99 + 2 * (size_t)NB * BCAP;
    float*    cntf      = sums + NG * HH2;
    int*      gcursor   = (int*)(cntf + NG);   // NB entries

    // ---- init + bucketed CSR build (fixed-capacity buckets, LDS-sorted scatter) ----
    k_init<<<(NG * HH2 + NG + 255) / 256, 256, 0, stream>>>(gcursor, sums);
    k_bscatter<<<NBLK_B, 256, 0, stream>>>(src, dst, gcursor, pairs, NE);
    k_csr<<<NB, 512, 0, stream>>>(pairs, gcursor, row_start, rend, dinv, esrc);

    const int gblk = (NN + 127) / 128;   // 782

    // ---- layer 1: h1b = fp8(dinv[row] * (x @ W1)) via MFMA ----
    k_mfma<128, false><<<gblk, 256, 0, stream>>>(x, W1, h1b, dinv, NN);
    k_agg1<<<(NN * 64 + 255) / 256, 256, 0, stream>>>(row_start, rend, esrc, dinv,
                                                      (const uint2*)h1b, b1,
                                                      (uint4*)relu1, NN);

    // ---- layer 2: h2b = fp8(dinv[row] * (relu1 @ W2)) via MFMA ----
    k_mfma<64, true><<<gblk, 256, 0, stream>>>(relu1, W2, h2b, dinv, NN);
    k_agg2<<<(NN * 64 + 255) / 256, 256, 0, stream>>>(row_start, rend, esrc, dinv,
                                                      (const uint2*)h2b, b2,
                                                      (uint2*)v2, NN);

    // ---- pool ----
    {
        const int waves = (NN + 127) / 128;
        const int blocks = (waves * 64 + 255) / 256;
        k_pool<<<blocks, 256, 0, stream>>>(v2, bat, sums, cntf, NN);
    }

    // ---- final FC ----
    k_fc<<<1, 640, 0, stream>>>(sums, cntf, Wfc, bfc, out);
}